// Round 1
// baseline (310.843 us; speedup 1.0000x reference)
//
#include <hip/hip_runtime.h>

#define LOGZERO (-1.0e10f)

constexpr int BS    = 16;
constexpr int XMAX  = 512;
constexpr int VOCAB = 4000;
constexpr int YMAX  = 64;
constexpr int L     = 2 * YMAX + 1;   // 129 path states
constexpr int NT    = 192;            // 3 waves; threads 0..128 hold states
constexpr int PF    = 8;              // prefetch depth for the lpp gather

// output layout (flat float32, in reference return order)
constexpr size_t AS_OFF = 0;                                   // aligned_seq [16][512]
constexpr size_t TM_OFF = (size_t)BS * XMAX;                   // trigger_mask [16][65][512]
constexpr size_t YL_OFF = TM_OFF + (size_t)BS * (YMAX + 1) * XMAX; // ylens+1 [16]
constexpr size_t SC_OFF = YL_OFF + BS;                         // score [16]

__global__ __launch_bounds__(NT)
void ctc_viterbi_kernel(const float* __restrict__ ctc,
                        const int* __restrict__ src_size,
                        const int* __restrict__ ys,
                        const int* __restrict__ ylens,
                        const int* __restrict__ blank_p,
                        float* __restrict__ out)
{
    const int b    = blockIdx.x;
    const int tid  = threadIdx.x;
    const int lane = tid & 63;
    const int w    = tid >> 6;

    const int blank = blank_p[0];
    const int ss    = src_size[b];        // valid frames for this batch elem
    const int ylen  = ylens[b];
    const int plen  = 2 * ylen + 1;       // path length

    // alpha double buffer with 2-pad at front (for l-1, l-2) and 2-pad at back
    __shared__ float alpha[2][2 + NT + 2];
    __shared__ int   pathS[NT];
    __shared__ float afinal[L];
    __shared__ unsigned long long B0[XMAX][3];   // bit-plane 0 of bp code
    __shared__ unsigned long long B1[XMAX][3];   // bit-plane 1 of bp code
    __shared__ int   states[XMAX];               // aligned_states, later collapsed seq
    __shared__ int   seq[XMAX];                  // pre-collapse aligned_seq
    __shared__ int   trig[XMAX];

    // blank-interleaved path: even -> blank, odd -> ys[(l-1)/2]
    int pl = blank;
    if (tid < L && (tid & 1)) pl = ys[b * YMAX + ((tid - 1) >> 1)];
    pathS[tid] = pl;

    alpha[0][2 + tid] = (tid == 0) ? 0.0f : LOGZERO;   // alpha0
    alpha[1][2 + tid] = LOGZERO;
    if (tid < 2) {
        alpha[0][tid] = LOGZERO;            alpha[1][tid] = LOGZERO;
        alpha[0][2 + NT + tid] = LOGZERO;   alpha[1][2 + NT + tid] = LOGZERO;
    }
    __syncthreads();

    // same_transition: m2 forbidden when path[l-2]==path[l]; also for l<2 and pads
    int same = 1;
    if (tid >= 2 && tid < L) same = (pathS[tid - 2] == pathS[tid]) ? 1 : 0;

    // gather base for this thread's path label column
    const float* cbase = ctc + (size_t)b * XMAX * VOCAB + pl;

    // register ring prefetch of lpp
    float rbuf[PF];
    #pragma unroll
    for (int k = 0; k < PF; ++k)
        rbuf[k] = (tid < L) ? cbase[(size_t)k * VOCAB] : LOGZERO;

    float aown = (tid == 0) ? 0.0f : LOGZERO;  // own alpha in register
    int cur = 0;

    for (int tb = 0; tb < XMAX; tb += PF) {
        #pragma unroll
        for (int k = 0; k < PF; ++k) {
            const int t = tb + k;
            const float lpv = (tid < L && t < ss) ? rbuf[k] : LOGZERO;
            if (tid < L && t + PF < XMAX)
                rbuf[k] = cbase[(size_t)(t + PF) * VOCAB];

            const float m0 = aown;
            const float m1 = alpha[cur][1 + tid];
            const float m2 = same ? LOGZERO : alpha[cur][tid];

            // argmax with first-occurrence tie-break: m0 > m1 > m2
            float best = m0; int idx = 0;
            if (m1 > best) { best = m1; idx = 1; }
            if (m2 > best) { best = m2; idx = 2; }

            // pack 2-bit bp code via per-wave ballots (uniform control flow here)
            const unsigned long long b0m = __ballot(idx & 1);
            const unsigned long long b1m = __ballot(idx >> 1);
            if (lane == 0) { B0[t][w] = b0m; B1[t][w] = b1m; }

            const float mp   = (tid >= plen) ? LOGZERO : best;  // "outside" mask
            const float anew = mp + lpv;

            if (tid < L) {
                alpha[cur ^ 1][2 + tid] = anew;
                if (t == ss - 1) afinal[tid] = anew;   // alpha at final valid frame
            }
            aown = anew;
            cur ^= 1;
            __syncthreads();
        }
    }

    // ---- scores, init state, sequential backtrace (one thread per block) ----
    if (tid == 0) {
        const float s1 = afinal[plen - 1];
        const float s2 = afinal[plen - 2];
        const int   ist = (s1 > s2) ? (plen - 1) : (plen - 2);
        out[SC_OFF + b] = fmaxf(s1, s2);
        out[YL_OFF + b] = (float)(ylen + 1);

        int curSt = 0;
        for (int t = XMAX - 1; t >= 0; --t) {
            const int ct = (t == ss - 1) ? ist : curSt;
            states[t] = (t <= ss - 1) ? ct : 0;
            int nxt = ct;
            if (t >= 1 && t <= ss - 1) {
                const int wA = ct >> 6, bit = ct & 63;
                const int code = (int)((B0[t][wA] >> bit) & 1ULL)
                               | (((int)((B1[t][wA] >> bit) & 1ULL)) << 1);
                nxt = ct - code;   // bp = l - argmax
            }
            curSt = nxt;
        }
    }
    __syncthreads();

    // ---- states -> labels ----
    for (int t = tid; t < XMAX; t += NT) seq[t] = pathS[states[t]];
    __syncthreads();

    // collapse repeats (compare against ORIGINAL left neighbor), write aligned_seq
    for (int t = tid; t < XMAX; t += NT) {
        const int prev = t ? seq[t - 1] : 0;
        const int v = (seq[t] == prev) ? 0 : seq[t];
        states[t] = v;                             // reuse as collapsed seq
        out[AS_OFF + (size_t)b * XMAX + t] = (float)v;
    }
    __syncthreads();

    // inclusive cumsum of (shifted collapsed != blank)
    if (tid == 0) {
        int s = 0;
        #pragma unroll 8
        for (int t = 0; t < XMAX; ++t) {
            const int sh = t ? states[t - 1] : 0;
            s += (sh != blank) ? 1 : 0;
            trig[t] = s;
        }
    }
    __syncthreads();

    // trigger mask rows 0..64; row 64 gets src-mask AND + forced True at ss-1
    float* tm = out + TM_OFF + (size_t)b * (YMAX + 1) * XMAX;
    for (int i = tid; i < (YMAX + 1) * XMAX; i += NT) {
        const int y = i >> 9;          // / XMAX
        const int t = i & (XMAX - 1);
        bool v;
        if (y == YMAX) v = ((trig[t] == YMAX) && (t < ss)) || (t == ss - 1);
        else           v = (trig[t] == y);
        tm[i] = v ? 1.0f : 0.0f;
    }
}

extern "C" void kernel_launch(void* const* d_in, const int* in_sizes, int n_in,
                              void* d_out, int out_size, void* d_ws, size_t ws_size,
                              hipStream_t stream) {
    (void)in_sizes; (void)n_in; (void)d_ws; (void)ws_size; (void)out_size;
    const float* ctc      = (const float*)d_in[0];
    // d_in[1] = src_mask (bool) — derivable from src_size, unused
    const int*   src_size = (const int*)d_in[2];
    const int*   ys       = (const int*)d_in[3];
    const int*   ylens    = (const int*)d_in[4];
    const int*   blank    = (const int*)d_in[5];
    float*       out      = (float*)d_out;

    ctc_viterbi_kernel<<<BS, NT, 0, stream>>>(ctc, src_size, ys, ylens, blank, out);
}